// Round 9
// baseline (108.917 us; speedup 1.0000x reference)
//
#include <hip/hip_runtime.h>
#include <hip/hip_bf16.h>

#define B 32
#define S 8192
#define D 512
#define CODE_START 256
#define CODE_END 257
#define MEM_TOK 258
#define ADDR_KEY 206
#define MEM_STORE 455
#define CHUNK 512
#define NCH (S / CHUNK)  // 16 chunks per row
#define TPB 128          // tokens per main-kernel block

typedef float f32x4 __attribute__((ext_vector_type(4)));
typedef int i32x4 __attribute__((ext_vector_type(4)));

__device__ inline int make_pack(int tk, int cs, int p, int f, int mhe) {
  int pk = tk;
  if ((cs >= 0) && (p < f) && (tk < 256)) {
    int sp = p - cs - 1;
    if (sp < 0) sp = 0;
    int q = sp / 5;
    int r = sp - q * 5;
    int addr = q * 8 + r;
    pk |= (1 << 9) | ((addr & 15) << 12) | (((addr >> 4) & 15) << 16) |
          (((addr >> 8) & 15) << 20);
  }
  if (tk == MEM_TOK && p < mhe) pk |= (1 << 10);
  return pk;
}

// ---------------------------------------------------------------------------
// Kernel A (unchanged from round 8): per-token pack word.
// ---------------------------------------------------------------------------
__global__ __launch_bounds__(256) void nvm_pack(
    const int* __restrict__ tok, const int* __restrict__ mhe_p,
    int* __restrict__ pack) {
  const int c = blockIdx.x, b = blockIdx.y;
  const int tid = threadIdx.x;
  const int lane = tid & 63, wid = tid >> 6;
  const int base = c * CHUNK;
  const int* row = tok + b * S;

  __shared__ int red_max[4], red_min[4], wt[4];

  const int s0 = base + 2 * tid, s1 = s0 + 1;
  const int2 tt = reinterpret_cast<const int2*>(row + base)[tid];
  const int v0 = (tt.x == CODE_START) ? s0 : -1;
  const int v1 = (tt.y == CODE_START) ? s1 : -1;
  const int i1 = max(v0, v1);
  int incl = i1;
  #pragma unroll
  for (int off = 1; off < 64; off <<= 1) {
    const int u = __shfl_up(incl, off, 64);
    if (lane >= off) incl = max(incl, u);
  }
  int ex = __shfl_up(incl, 1, 64);
  if (lane == 0) ex = -1;
  if (lane == 63) wt[wid] = incl;

  int vmax = -1, vmin = S;
  #pragma unroll
  for (int k = 0; k < 8; ++k) {
    const i32x4 q = reinterpret_cast<const i32x4*>(row)[tid + 256 * k];
    const int p = 4 * (tid + 256 * k);
    #pragma unroll
    for (int e = 0; e < 4; ++e) {
      const int t = q[e], pp = p + e;
      if (t == CODE_START && pp < base) vmax = max(vmax, pp);
      if (t == CODE_END) vmin = min(vmin, pp);
    }
  }
  #pragma unroll
  for (int off = 32; off; off >>= 1) {
    vmax = max(vmax, __shfl_down(vmax, off, 64));
    vmin = min(vmin, __shfl_down(vmin, off, 64));
  }
  if (lane == 0) { red_max[wid] = vmax; red_min[wid] = vmin; }
  __syncthreads();

  int pre = max(max(red_max[0], red_max[1]), max(red_max[2], red_max[3]));
  for (int w = 0; w < wid; ++w) pre = max(pre, wt[w]);
  const int fce = min(min(red_min[0], red_min[1]), min(red_min[2], red_min[3]));
  const int mhe = mhe_p[0];

  ex = max(ex, pre);
  const int cs0 = max(ex, v0);
  const int cs1 = max(ex, i1);

  pack[b * S + s0] = make_pack(tt.x, cs0, s0, fce, mhe);
  pack[b * S + s1] = make_pack(tt.y, cs1, s1, fce, mhe);
}

// ---------------------------------------------------------------------------
// Kernel M: contiguous 128-token segment per block. LDS-staged pack words,
// then stream: LDS broadcast + table f32x4 load + nt store per 16 B.
// ---------------------------------------------------------------------------
__global__ __launch_bounds__(256) void nvm_main(
    const int* __restrict__ pack, const float* __restrict__ table,
    float* __restrict__ out) {
  __shared__ int pk[TPB];
  const int tbase = blockIdx.x * TPB;
  if (threadIdx.x < TPB / 4) {
    reinterpret_cast<i32x4*>(pk)[threadIdx.x] =
        reinterpret_cast<const i32x4*>(pack + tbase)[threadIdx.x];
  }
  __syncthreads();

  const int lane = threadIdx.x & 127;
  const int half = threadIdx.x >> 7;
  const int c0 = lane * 4;
  float* outb = out + (size_t)tbase * D + c0;

  #pragma unroll 4
  for (int j = 0; j < TPB / 2; ++j) {
    const int i = 2 * j + half;
    const int p = pk[i];
    const int tk = p & 511;
    f32x4 v = *reinterpret_cast<const f32x4*>(table + tk * D + c0);
    if (p & (1 << 9)) {
      const int ca = ADDR_KEY + ((p >> 12) & 15);
      const int cb = ADDR_KEY + 16 + ((p >> 16) & 15);
      const int cc = ADDR_KEY + 32 + ((p >> 20) & 15);
      #pragma unroll
      for (int u = 0; u < 4; ++u) {
        const int ch = c0 + u;
        if (ch == ca || ch == cb || ch == cc) v[u] = 1.0f;
      }
    }
    if ((p & (1 << 10)) && c0 == (MEM_STORE & ~3)) v[MEM_STORE & 3] = 1.0f;
    __builtin_nontemporal_store(v, reinterpret_cast<f32x4*>(outb + (size_t)i * D));
  }
}

extern "C" void kernel_launch(void* const* d_in, const int* in_sizes, int n_in,
                              void* d_out, int out_size, void* d_ws, size_t ws_size,
                              hipStream_t stream) {
  const int* tok = (const int*)d_in[0];
  const float* table = (const float*)d_in[1];
  const int* mhe = (const int*)d_in[2];
  float* out = (float*)d_out;

  int* pack = (int*)d_ws;  // B*S ints = 1 MiB

  nvm_pack<<<dim3(NCH, B), 256, 0, stream>>>(tok, mhe, pack);
  nvm_main<<<(B * S) / TPB, 256, 0, stream>>>(pack, table, out);
}

// Round 10
// 100.802 us; speedup vs baseline: 1.0805x; 1.0805x over previous
//
#include <hip/hip_runtime.h>
#include <hip/hip_bf16.h>

#define B 32
#define S 8192
#define D 512
#define CODE_START 256
#define CODE_END 257
#define MEM_TOK 258
#define ADDR_KEY 206
#define MEM_STORE 455
#define CHUNK 512
#define NCH (S / CHUNK)  // 16 chunks per row

typedef float f32x4 __attribute__((ext_vector_type(4)));

// ---------------------------------------------------------------------------
// Kernel A: per-chunk local scan. Grid (NCH, B), 256 threads, 2 tokens/thread.
// ---------------------------------------------------------------------------
__global__ __launch_bounds__(256) void nvm_chunk_scan(
    const int* __restrict__ tok, int* __restrict__ cs_local,
    int* __restrict__ carry, int* __restrict__ mince) {
  const int c = blockIdx.x;
  const int b = blockIdx.y;
  const int tid = threadIdx.x;
  const int lane = tid & 63;
  const int wid = tid >> 6;
  const int base = c * CHUNK;
  const int* row = tok + b * S;

  const int s0 = base + 2 * tid, s1 = s0 + 1;
  const int t0 = row[s0], t1 = row[s1];
  int v0 = (t0 == CODE_START) ? s0 : -1;
  int v1 = (t1 == CODE_START) ? s1 : -1;
  const int i1 = max(v0, v1);  // pair-inclusive

  // wave-64 inclusive max scan over pair totals
  int incl = i1;
  #pragma unroll
  for (int off = 1; off < 64; off <<= 1) {
    int u = __shfl_up(incl, off, 64);
    if (lane >= off) incl = max(incl, u);
  }
  int ex = __shfl_up(incl, 1, 64);
  if (lane == 0) ex = -1;

  // min CODE_END reduce
  int m = min((t0 == CODE_END) ? s0 : S, (t1 == CODE_END) ? s1 : S);
  #pragma unroll
  for (int off = 32; off; off >>= 1) m = min(m, __shfl_down(m, off, 64));

  __shared__ int wt[4], wm[4];
  if (lane == 63) wt[wid] = incl;
  if (lane == 0) wm[wid] = m;
  __syncthreads();

  int pre = -1;
  for (int w = 0; w < wid; ++w) pre = max(pre, wt[w]);
  ex = max(ex, pre);
  cs_local[b * S + s0] = max(ex, v0);
  cs_local[b * S + s1] = max(ex, i1);

  if (tid == 0) {
    carry[b * NCH + c] = max(max(wt[0], wt[1]), max(wt[2], wt[3]));
    mince[b * NCH + c] = min(min(wm[0], wm[1]), min(wm[2], wm[3]));
  }
}

// ---------------------------------------------------------------------------
// Kernel B: per-row exclusive prefix-max over chunk carries + fce reduce.
// ---------------------------------------------------------------------------
__global__ __launch_bounds__(64) void nvm_row_prefix(
    const int* __restrict__ carry, const int* __restrict__ mince,
    int* __restrict__ pre, int* __restrict__ fce) {
  const int b = threadIdx.x;
  if (b < B) {
    int run = -1, mn = S;
    for (int c = 0; c < NCH; ++c) {
      pre[b * NCH + c] = run;
      run = max(run, carry[b * NCH + c]);
      mn = min(mn, mince[b * NCH + c]);
    }
    fce[b] = mn;
  }
}

// ---------------------------------------------------------------------------
// Kernel M: gather + patch + nontemporal stream out.
// 128 threads per token (one float4 each), 2 tokens per block-iteration,
// grid-stride over token pairs.
// ---------------------------------------------------------------------------
__global__ __launch_bounds__(256) void nvm_main(
    const int* __restrict__ tok, const float* __restrict__ table,
    const int* __restrict__ cs_local, const int* __restrict__ pre,
    const int* __restrict__ fce, const int* __restrict__ mhe_p,
    float* __restrict__ out) {
  const int lane = threadIdx.x & 127;
  const int half = threadIdx.x >> 7;
  const int mhe = mhe_p[0];
  const int NTP = B * S / 2;
  const int c0 = lane * 4;

  for (int tp = blockIdx.x; tp < NTP; tp += gridDim.x) {
    const int t = tp * 2 + half;
    const int b = t >> 13;
    const int s = t & (S - 1);

    const int tk = tok[t];
    const int cs = max(cs_local[t], pre[b * NCH + (s >> 9)]);
    const int f = fce[b];

    const bool maskAddr = (cs >= 0) && (s < f) && (tk < 256);
    int c1 = -1, c2 = -1, c3 = -1;
    if (maskAddr) {
      int sp = s - cs - 1;
      if (sp < 0) sp = 0;
      int q = sp / 5;
      int r = sp - q * 5;
      int addr = q * 8 + r;
      c1 = ADDR_KEY + (addr & 15);
      c2 = ADDR_KEY + 16 + ((addr >> 4) & 15);
      c3 = ADDR_KEY + 32 + ((addr >> 8) & 15);
    }
    const bool memM = (tk == MEM_TOK) && (s < mhe);

    f32x4 v = *reinterpret_cast<const f32x4*>(table + tk * D + c0);
    #pragma unroll
    for (int j = 0; j < 4; ++j) {
      int ch = c0 + j;
      bool hit = (maskAddr && (ch == c1 || ch == c2 || ch == c3)) ||
                 (memM && ch == MEM_STORE);
      if (hit) v[j] = 1.0f;
    }
    f32x4* dst = reinterpret_cast<f32x4*>(out + (size_t)t * D + c0);
    __builtin_nontemporal_store(v, dst);
  }
}

extern "C" void kernel_launch(void* const* d_in, const int* in_sizes, int n_in,
                              void* d_out, int out_size, void* d_ws, size_t ws_size,
                              hipStream_t stream) {
  const int* tok = (const int*)d_in[0];
  const float* table = (const float*)d_in[1];
  const int* mhe = (const int*)d_in[2];
  float* out = (float*)d_out;

  int* cs_local = (int*)d_ws;                 // B*S ints = 1 MiB
  int* carry = cs_local + B * S;              // B*NCH
  int* mince = carry + B * NCH;               // B*NCH
  int* pre = mince + B * NCH;                 // B*NCH
  int* fce = pre + B * NCH;                   // B

  nvm_chunk_scan<<<dim3(NCH, B), 256, 0, stream>>>(tok, cs_local, carry, mince);
  nvm_row_prefix<<<1, 64, 0, stream>>>(carry, mince, pre, fce);
  nvm_main<<<4096, 256, 0, stream>>>(tok, table, cs_local, pre, fce, mhe, out);
}